// Round 8
// baseline (919.476 us; speedup 1.0000x reference)
//
#include <hip/hip_runtime.h>

#define NC 512   // N_CLUSTERS

// ===========================================================================
// Pre-pass: dstT[w][s] = (u16)src[s][w]  (verified R3/R5/R6/R7).
// ===========================================================================
__global__ __launch_bounds__(256) void k_transpose_pack(
    const int* __restrict__ src, unsigned short* __restrict__ dst)
{
    __shared__ unsigned short tile[64][65];
    int tx = blockIdx.x % 8, ty = blockIdx.x / 8;
    int lane = threadIdx.x & 63, grp = threadIdx.x >> 6;
    for (int r = grp * 16; r < grp * 16 + 16; ++r)
        tile[r][lane] = (unsigned short)src[(ty * 64 + r) * NC + tx * 64 + lane];
    __syncthreads();
    for (int r = grp * 16; r < grp * 16 + 16; ++r)
        dst[(tx * 64 + r) * NC + ty * 64 + lane] = tile[lane][r];
}

// add16[i][j] = (u16)add_lut[i][j]  (verified R3/R6).
__global__ __launch_bounds__(256) void k_pack_add(
    const int* __restrict__ src, unsigned short* __restrict__ dst)
{
    int base = blockIdx.x * 1024 + threadIdx.x;
    for (int i = 0; i < 4; ++i) dst[base + i * 256] = (unsigned short)src[base + i * 256];
}

// ===========================================================================
// Stage 1: discretize -> u16 symbols (verified R1..R7).
// ===========================================================================
__global__ __launch_bounds__(256) void k_discretize(
    const float* __restrict__ x, const float* __restrict__ cent,
    unsigned short* __restrict__ out)
{
    __shared__ float c[NC];
    int tid = threadIdx.x;
    for (int i = tid; i < NC; i += 256) c[i] = cent[i];
    __syncthreads();
    int id = blockIdx.x * 256 + tid;   // 131072 exact
    float px = x[id];
    float best = fabsf(px - c[0]);
    int bi = 0;
    for (int k = 1; k < NC; ++k) {
        float d = fabsf(px - c[k]);
        if (d < best) { best = d; bi = k; }
    }
    out[id] = (unsigned short)bi;
}

// ===========================================================================
// Nibble-bin pop-min scanner (verified R4/R7). 512 bins packed 8/word;
// in-register window = 4 VGPRs (32 bins) + nonzero mask.
// ===========================================================================
struct ScanN {
    uint32_t* base;
    uint32_t w[4];
    uint32_t mask;
    int chunk;

    static __device__ inline uint32_t nz4b(uint32_t x) {
        uint32_t y = (x & 0x7F7F7F7Fu) + 0x7F7F7F7Fu;
        y = (y | x) & 0x80808080u;
        return (y * 0x00204081u) >> 28;
    }
    static __device__ inline uint32_t spread4(uint32_t v) {
        v = (v | (v << 2)) & 0x33u;
        v = (v | (v << 1)) & 0x55u;
        return v;
    }
    static __device__ inline uint32_t nzn(uint32_t x) {
        uint32_t lo = x & 0x0F0F0F0Fu;
        uint32_t hi = (x >> 4) & 0x0F0F0F0Fu;
        return spread4(nz4b(lo)) | (spread4(nz4b(hi)) << 1);
    }
    __device__ inline void init(uint32_t* b) { base = b; mask = 0; chunk = -1; }
    __device__ inline void load() {
        uint4 a = *(const uint4*)(base + chunk * 4);
        w[0] = a.x; w[1] = a.y; w[2] = a.z; w[3] = a.w;
        mask = nzn(w[0]) | (nzn(w[1]) << 8) | (nzn(w[2]) << 16) | (nzn(w[3]) << 24);
    }
    __device__ inline void ensure() { while (mask == 0) { ++chunk; load(); } }
    __device__ inline int  peek()   { ensure(); return chunk * 32 + (int)__builtin_ctz(mask); }
    __device__ inline void consume_min() {
        int k = (int)__builtin_ctz(mask);
        int dw = k >> 3, sh = (k & 7) << 2;
        uint32_t cnt = 0;
#pragma unroll
        for (int i = 0; i < 4; ++i) if (i == dw) { cnt = (w[i] >> sh) & 0xFu; w[i] -= (1u << sh); }
        if (cnt == 1) mask &= ~(1u << k);
    }
    __device__ inline int pop() { int v = peek(); consume_min(); return v; }
    __device__ inline void insert(int v) {
        int rel = v - chunk * 32;
        if (rel < 32) {
            int dw = rel >> 3, sh = (rel & 7) << 2;
#pragma unroll
            for (int i = 0; i < 4; ++i) if (i == dw) w[i] += (1u << sh);
            mask |= (1u << rel);
        } else {
            uint32_t old = base[v >> 3];
            base[v >> 3] = old + (1u << ((v & 7) << 2));
        }
    }
};

// ===========================================================================
// conv1 — R7 verbatim (verified; control this round).
// 64 threads = 16 instances x 4 redundant lanes.
// ===========================================================================
template<typename IT, typename OT, int CIN, int CO, int IH, int IW, int OH, int OW>
__device__ __forceinline__ void conv_body(
    const IT* __restrict__ in_sym, const int* __restrict__ wsym,
    const unsigned short* __restrict__ convT, const int* __restrict__ add_lut,
    const int* __restrict__ bias_lut, const int* __restrict__ relu_lut,
    OT* __restrict__ out)
{
    constexpr int N    = 25 * CIN;
    constexpr int PPI  = OH * OW;
    constexpr int BPC  = (128 * PPI) / 16;
    constexpr int STR  = 68;
    __shared__ __align__(16) uint32_t bins[16 * STR];
    int tid = threadIdx.x;
    int il  = tid >> 2;
    int sub = tid & 3;

    for (int i = tid; i < 16 * STR; i += 64) bins[i] = 0u;

    int posg = blockIdx.x % BPC;
    int co   = blockIdx.x / BPC;
    int pos  = posg * 16 + il;
    int b  = pos / PPI;
    int yx = pos % PPI;
    int oy = yx / OW, ox = yx % OW;

    uint32_t* mybins = bins + il * STR;
    __syncthreads();

    for (int n = sub; n < N; n += 4) {
        int i   = n / (5 * CIN);
        int rem = n % (5 * CIN);
        int j   = rem / CIN;
        int c   = rem % CIN;
        int s = (int)in_sym[((b * IH + (oy * 2 + i)) * IW + (ox * 2 + j)) * CIN + c];
        int w = wsym[n * CO + co];
        int g = convT[w * NC + s];
        atomicAdd(&mybins[g >> 3], 1u << ((g & 7) << 2));
    }
    __syncthreads();

    ScanN sc; sc.init(mybins);
    int t = sc.pop();
    for (int j = 1; j < N; ++j) {
        int x = sc.pop();
        int t2 = add_lut[x * NC + t];
        if (j < N - 2) {
            int y = sc.peek();
            if (t2 > y) { sc.consume_min(); sc.insert(t2); t = y; }
            else t = t2;
        } else t = t2;
    }
    if (sub == 0)
        out[pos * CO + co] = (OT)relu_lut[bias_lut[t * CO + co]];
}

__global__ __launch_bounds__(64) void k_conv1(
    const unsigned short* in, const int* wsym, const unsigned short* convT,
    const int* add_lut, const int* bias, const int* relu, unsigned short* out)
{
    conv_body<unsigned short, unsigned short, 1, 6, 32, 32, 14, 14>(
        in, wsym, convT, add_lut, bias, relu, out);
}

// ===========================================================================
// conv2 — NEW: 128 threads = 128 instances (1 lane each), one co per block.
// Build: lane-private nibble bins via fire-and-forget LDS atomics; convT row
// wave-uniform (L1-hot across 25 same-co blocks); in_sym spatially local.
// Fold: add16 streamed through a 16-row LDS window (coalesced = streaming
// rate); pops ascend => forward-only window (divergent-lane structure
// correctness-verified in R6). LDS 50.8 KB => 3 blocks/CU.
// ===========================================================================
__global__ __launch_bounds__(128) void k_conv2(
    const unsigned short* __restrict__ in_sym,   // (B,14,14,6) u16
    const int* __restrict__ wsym,                // (150, 16)
    const unsigned short* __restrict__ convT,    // (NC,NC) [w][s]
    const unsigned short* __restrict__ add16,    // (NC,NC) u16
    const int* __restrict__ bias_lut,            // (NC, 16)
    const int* __restrict__ relu_lut,            // (NC,)
    int* __restrict__ out)                       // (B,5,5,16) int
{
    constexpr int N   = 150;
    constexpr int STR = 68;                      // words per instance (272B)
    __shared__ __align__(16) uint32_t bins[128 * STR];     // 34.8 KB
    __shared__ __align__(16) unsigned short win[16 * NC];  // 16 KB
    int tid = threadIdx.x;

    for (int i = tid; i < 128 * STR; i += 128) bins[i] = 0u;
    __syncthreads();

    int co   = blockIdx.x / 25;                  // wave-uniform
    int posg = blockIdx.x % 25;
    int pos  = posg * 128 + tid;                 // [0, 3200) within co
    int b  = pos / 25;
    int yx = pos % 25;
    int oy = yx / 5, ox = yx % 5;

    uint32_t* mybins = bins + tid * STR;
    for (int n = 0; n < N; ++n) {
        int i   = n / 30;
        int rem = n % 30;
        int j   = rem / 6;
        int c   = rem % 6;
        int s = (int)in_sym[((b * 14 + (oy * 2 + i)) * 14 + (ox * 2 + j)) * 6 + c];
        int w = wsym[n * 16 + co];               // uniform scalar
        int g = convT[w * NC + s];               // uniform 1KB row
        atomicAdd(&mybins[g >> 3], 1u << ((g & 7) << 2));   // fire-and-forget
    }
    __syncthreads();

    ScanN sc; sc.init(mybins);
    int t = sc.pop();
    int j = 1;
    int x = sc.pop();
    for (int r0 = 0; r0 < NC; r0 += 16) {
        const uint4* gsrc = (const uint4*)(add16 + r0 * NC);  // 16 rows = 16 KB
        uint4* wdst = (uint4*)win;
        for (int i = tid; i < 1024; i += 128) wdst[i] = gsrc[i];
        __syncthreads();
        while (j < N && x < r0 + 16) {
            int t2 = win[(x - r0) * NC + t];
            if (j < N - 2) {
                int y = sc.peek();
                if (t2 > y) { sc.consume_min(); sc.insert(t2); t = y; }
                else t = t2;
            } else t = t2;
            ++j;
            if (j < N) x = sc.pop();
        }
        __syncthreads();
    }
    out[pos * 16 + co] = relu_lut[bias_lut[t * 16 + co]];
}

// ===========================================================================
// FC — R7 verbatim (verified; controls this round).
// ===========================================================================
template<int M, int K, bool PERM>
__device__ __forceinline__ void fc_body(
    const int* __restrict__ in_sym, const int* __restrict__ wsym,
    const unsigned short* __restrict__ fcT, const int* __restrict__ add_lut,
    const int* __restrict__ bias_lut, const int* __restrict__ relu_lut,
    int* __restrict__ out)
{
    constexpr int STR = 68;
    __shared__ __align__(16) uint32_t bins[16 * STR];
    int tid = threadIdx.x;
    int il  = tid >> 2;
    int sub = tid & 3;

    for (int i = tid; i < 16 * STR; i += 64) bins[i] = 0u;

    int m  = blockIdx.x / 8;
    int bg = blockIdx.x % 8;
    int b  = bg * 16 + il;

    uint32_t* mybins = bins + il * STR;
    __syncthreads();

    for (int k = sub; k < K; k += 4) {
        int xaddr;
        if (PERM) { int c = k / 25, yx = k % 25; xaddr = b * 400 + yx * 16 + c; }
        else      { xaddr = k * 128 + b; }
        int x = in_sym[xaddr];
        int w = wsym[m * K + k];
        int g = fcT[w * NC + x];
        atomicAdd(&mybins[g >> 3], 1u << ((g & 7) << 2));
    }
    __syncthreads();

    ScanN sc; sc.init(mybins);
    int t = sc.pop();
    for (int s = 1; s < K; ++s) t = add_lut[sc.pop() * NC + t];
    if (sub == 0)
        out[m * 128 + b] = relu_lut[bias_lut[t * M + m]];
}

__global__ __launch_bounds__(64) void k_fc1(
    const int* in, const int* wsym, const unsigned short* fcT,
    const int* add_lut, const int* bias, const int* relu, int* out)
{
    fc_body<120, 400, true>(in, wsym, fcT, add_lut, bias, relu, out);
}

__global__ __launch_bounds__(64) void k_fc2(
    const int* in, const int* wsym, const unsigned short* fcT,
    const int* add_lut, const int* bias, const int* relu, int* out)
{
    fc_body<84, 120, false>(in, wsym, fcT, add_lut, bias, relu, out);
}

// ===========================================================================
// Head — verified R1/R7 (m-major input).
// ===========================================================================
__global__ __launch_bounds__(64) void k_head(
    const int* __restrict__ f2m, const float* __restrict__ cent,
    const float* __restrict__ w, const float* __restrict__ bias,
    float* __restrict__ out)
{
    int b = blockIdx.x * 64 + threadIdx.x;
    float acc[10];
#pragma unroll
    for (int o = 0; o < 10; ++o) acc[o] = bias[o];
    for (int k = 0; k < 84; ++k) {
        float f = cent[f2m[k * 128 + b]];
#pragma unroll
        for (int o = 0; o < 10; ++o) acc[o] += f * w[o * 84 + k];
    }
    float mx = acc[0];
#pragma unroll
    for (int o = 1; o < 10; ++o) mx = fmaxf(mx, acc[o]);
    float s = 0.f;
#pragma unroll
    for (int o = 0; o < 10; ++o) { acc[o] = expf(acc[o] - mx); s += acc[o]; }
    float inv = 1.f / s;
#pragma unroll
    for (int o = 0; o < 10; ++o) out[b * 10 + o] = acc[o] * inv;
}

// ===========================================================================
extern "C" void kernel_launch(void* const* d_in, const int* in_sizes, int n_in,
                              void* d_out, int out_size, void* d_ws, size_t ws_size,
                              hipStream_t stream)
{
    const float* x_bat  = (const float*)d_in[0];
    const float* cent   = (const float*)d_in[1];
    const int* conv_lut = (const int*)d_in[2];
    const int* fc_lut   = (const int*)d_in[3];
    const int* add_lut  = (const int*)d_in[4];
    const int* relu_lut = (const int*)d_in[5];
    const int* c1_bias  = (const int*)d_in[6];
    const int* c2_bias  = (const int*)d_in[7];
    const int* f1_bias  = (const int*)d_in[8];
    const int* f2_bias  = (const int*)d_in[9];
    const int* c1f      = (const int*)d_in[10];
    const int* c2f      = (const int*)d_in[11];
    const int* f1f      = (const int*)d_in[12];
    const int* f2f      = (const int*)d_in[13];
    const float* fc3_w  = (const float*)d_in[14];
    const float* fc3_b  = (const float*)d_in[15];
    float* out = (float*)d_out;

    char* ws = (char*)d_ws;
    unsigned short* convT = (unsigned short*)(ws);            // 512 KB
    unsigned short* fcT   = (unsigned short*)(ws + 524288);   // 512 KB
    unsigned short* add16 = (unsigned short*)(ws + 1048576);  // 512 KB
    unsigned short* sym0  = (unsigned short*)(ws + 1572864);  // 256 KB
    unsigned short* c1o   = (unsigned short*)(ws + 1835008);  // 294 KB (b,14,14,6) u16
    int* c2o = (int*)(ws + 2136064);                          // 200 KB (b,5,5,16)
    int* f1o = (int*)(ws + 2340864);                          //  60 KB (120,128) m-major
    int* f2o = (int*)(ws + 2402304);                          //  42 KB (84,128)  m-major
    // peak ws ~2.39 MB

    k_transpose_pack<<<64, 256, 0, stream>>>(conv_lut, convT);
    k_transpose_pack<<<64, 256, 0, stream>>>(fc_lut, fcT);
    k_pack_add<<<256, 256, 0, stream>>>(add_lut, add16);
    k_discretize<<<512, 256, 0, stream>>>(x_bat, cent, sym0);
    // conv1: R7 structure, 9408 blocks
    k_conv1<<<9408, 64, 0, stream>>>(sym0, c1f, convT, add_lut, c1_bias, relu_lut, c1o);
    // conv2: windowed fold, 16 co x 25 pos-groups = 400 blocks x 128 inst
    k_conv2<<<400, 128, 0, stream>>>(c1o, c2f, convT, add16, c2_bias, relu_lut, c2o);
    // fc1/fc2: R7 structure
    k_fc1<<<960, 64, 0, stream>>>(c2o, f1f, fcT, add_lut, f1_bias, relu_lut, f1o);
    k_fc2<<<672, 64, 0, stream>>>(f1o, f2f, fcT, add_lut, f2_bias, relu_lut, f2o);
    k_head<<<2, 64, 0, stream>>>(f2o, cent, fc3_w, fc3_b, out);
}

// Round 9
// 817.244 us; speedup vs baseline: 1.1251x; 1.1251x over previous
//
#include <hip/hip_runtime.h>

#define NC 512   // N_CLUSTERS

// ===========================================================================
// Pre-pass: dstT[w][s] = (u16)src[s][w]  (verified R3/R5/R6/R7/R8).
// ===========================================================================
__global__ __launch_bounds__(256) void k_transpose_pack(
    const int* __restrict__ src, unsigned short* __restrict__ dst)
{
    __shared__ unsigned short tile[64][65];
    int tx = blockIdx.x % 8, ty = blockIdx.x / 8;
    int lane = threadIdx.x & 63, grp = threadIdx.x >> 6;
    for (int r = grp * 16; r < grp * 16 + 16; ++r)
        tile[r][lane] = (unsigned short)src[(ty * 64 + r) * NC + tx * 64 + lane];
    __syncthreads();
    for (int r = grp * 16; r < grp * 16 + 16; ++r)
        dst[(tx * 64 + r) * NC + ty * 64 + lane] = tile[lane][r];
}

// ===========================================================================
// Stage 1: discretize -> u16 symbols (verified R1..R8).
// ===========================================================================
__global__ __launch_bounds__(256) void k_discretize(
    const float* __restrict__ x, const float* __restrict__ cent,
    unsigned short* __restrict__ out)
{
    __shared__ float c[NC];
    int tid = threadIdx.x;
    for (int i = tid; i < NC; i += 256) c[i] = cent[i];
    __syncthreads();
    int id = blockIdx.x * 256 + tid;   // 131072 exact
    float px = x[id];
    float best = fabsf(px - c[0]);
    int bi = 0;
    for (int k = 1; k < NC; ++k) {
        float d = fabsf(px - c[k]);
        if (d < best) { best = d; bi = k; }
    }
    out[id] = (unsigned short)bi;
}

// ===========================================================================
// Nibble-bin pop-min scanner (verified R4/R7/R8). 512 bins packed 8/word;
// in-register window = 4 VGPRs (32 bins) + nonzero mask. insert() far-path is
// plain RMW: all redundant lanes of an instance write same addr/value => +1
// exactly once (verified R7 at SUB=4; identical lockstep argument any SUB).
// ===========================================================================
struct ScanN {
    uint32_t* base;
    uint32_t w[4];
    uint32_t mask;
    int chunk;

    static __device__ inline uint32_t nz4b(uint32_t x) {
        uint32_t y = (x & 0x7F7F7F7Fu) + 0x7F7F7F7Fu;
        y = (y | x) & 0x80808080u;
        return (y * 0x00204081u) >> 28;
    }
    static __device__ inline uint32_t spread4(uint32_t v) {
        v = (v | (v << 2)) & 0x33u;
        v = (v | (v << 1)) & 0x55u;
        return v;
    }
    static __device__ inline uint32_t nzn(uint32_t x) {
        uint32_t lo = x & 0x0F0F0F0Fu;
        uint32_t hi = (x >> 4) & 0x0F0F0F0Fu;
        return spread4(nz4b(lo)) | (spread4(nz4b(hi)) << 1);
    }
    __device__ inline void init(uint32_t* b) { base = b; mask = 0; chunk = -1; }
    __device__ inline void load() {
        uint4 a = *(const uint4*)(base + chunk * 4);
        w[0] = a.x; w[1] = a.y; w[2] = a.z; w[3] = a.w;
        mask = nzn(w[0]) | (nzn(w[1]) << 8) | (nzn(w[2]) << 16) | (nzn(w[3]) << 24);
    }
    __device__ inline void ensure() { while (mask == 0) { ++chunk; load(); } }
    __device__ inline int  peek()   { ensure(); return chunk * 32 + (int)__builtin_ctz(mask); }
    __device__ inline void consume_min() {
        int k = (int)__builtin_ctz(mask);
        int dw = k >> 3, sh = (k & 7) << 2;
        uint32_t cnt = 0;
#pragma unroll
        for (int i = 0; i < 4; ++i) if (i == dw) { cnt = (w[i] >> sh) & 0xFu; w[i] -= (1u << sh); }
        if (cnt == 1) mask &= ~(1u << k);
    }
    __device__ inline int pop() { int v = peek(); consume_min(); return v; }
    __device__ inline void insert(int v) {
        int rel = v - chunk * 32;
        if (rel < 32) {
            int dw = rel >> 3, sh = (rel & 7) << 2;
#pragma unroll
            for (int i = 0; i < 4; ++i) if (i == dw) w[i] += (1u << sh);
            mask |= (1u << rel);
        } else {
            uint32_t old = base[v >> 3];
            base[v >> 3] = old + (1u << ((v & 7) << 2));
        }
    }
};

// ===========================================================================
// Cooperative symbolic conv, _conv_reduce semantics (verified R1/R2/R5/R7).
// 64 threads = (64/SUB) instances x SUB redundant lanes. Build: lanes split
// items via LDS nibble atomics over uniform convT rows; fold: redundant-lane
// direct add_lut gathers (64/SUB distinct lines per wave-instr).
// ===========================================================================
template<typename IT, typename OT, int CIN, int CO, int IH, int IW, int OH, int OW, int SUB>
__device__ __forceinline__ void conv_body(
    const IT* __restrict__ in_sym, const int* __restrict__ wsym,
    const unsigned short* __restrict__ convT, const int* __restrict__ add_lut,
    const int* __restrict__ bias_lut, const int* __restrict__ relu_lut,
    OT* __restrict__ out)
{
    constexpr int N    = 25 * CIN;
    constexpr int PPI  = OH * OW;
    constexpr int IPB  = 64 / SUB;              // instances per block
    constexpr int BPC  = (128 * PPI) / IPB;     // blocks per co (exact)
    constexpr int STR  = 68;
    __shared__ __align__(16) uint32_t bins[IPB * STR];
    int tid = threadIdx.x;
    int il  = tid / SUB;
    int sub = tid % SUB;

    for (int i = tid; i < IPB * STR; i += 64) bins[i] = 0u;

    int posg = blockIdx.x % BPC;
    int co   = blockIdx.x / BPC;                // wave-uniform
    int pos  = posg * IPB + il;
    int b  = pos / PPI;
    int yx = pos % PPI;
    int oy = yx / OW, ox = yx % OW;

    uint32_t* mybins = bins + il * STR;
    __syncthreads();

    for (int n = sub; n < N; n += SUB) {
        int i   = n / (5 * CIN);
        int rem = n % (5 * CIN);
        int j   = rem / CIN;
        int c   = rem % CIN;
        int s = (int)in_sym[((b * IH + (oy * 2 + i)) * IW + (ox * 2 + j)) * CIN + c];
        int w = wsym[n * CO + co];
        int g = convT[w * NC + s];
        atomicAdd(&mybins[g >> 3], 1u << ((g & 7) << 2));
    }
    __syncthreads();

    // Fold: all SUB lanes of an instance run the identical chain (lockstep).
    ScanN sc; sc.init(mybins);
    int t = sc.pop();
    for (int j = 1; j < N; ++j) {
        int x = sc.pop();
        int t2 = add_lut[x * NC + t];           // IPB distinct lines per wave
        if (j < N - 2) {
            int y = sc.peek();
            if (t2 > y) { sc.consume_min(); sc.insert(t2); t = y; }
            else t = t2;
        } else t = t2;
    }
    if (sub == 0)
        out[pos * CO + co] = (OT)relu_lut[bias_lut[t * CO + co]];
}

__global__ __launch_bounds__(64) void k_conv1(
    const unsigned short* in, const int* wsym, const unsigned short* convT,
    const int* add_lut, const int* bias, const int* relu, unsigned short* out)
{
    conv_body<unsigned short, unsigned short, 1, 6, 32, 32, 14, 14, 4>(
        in, wsym, convT, add_lut, bias, relu, out);
}

__global__ __launch_bounds__(64) void k_conv2(
    const unsigned short* in, const int* wsym, const unsigned short* convT,
    const int* add_lut, const int* bias, const int* relu, int* out)
{
    conv_body<unsigned short, int, 6, 16, 14, 14, 5, 5, 8>(
        in, wsym, convT, add_lut, bias, relu, out);
}

// ===========================================================================
// Cooperative symbolic FC, _fc_reduce = ascending pops (verified R1/R2/R7).
// 64 threads = (64/SUB) instances x SUB lanes; m wave-uniform.
// ===========================================================================
template<int M, int K, bool PERM, int SUB>
__device__ __forceinline__ void fc_body(
    const int* __restrict__ in_sym, const int* __restrict__ wsym,
    const unsigned short* __restrict__ fcT, const int* __restrict__ add_lut,
    const int* __restrict__ bias_lut, const int* __restrict__ relu_lut,
    int* __restrict__ out)
{
    constexpr int IPB = 64 / SUB;
    constexpr int BG  = 128 / IPB;             // batch groups
    constexpr int STR = 68;
    __shared__ __align__(16) uint32_t bins[IPB * STR];
    int tid = threadIdx.x;
    int il  = tid / SUB;
    int sub = tid % SUB;

    for (int i = tid; i < IPB * STR; i += 64) bins[i] = 0u;

    int m  = blockIdx.x / BG;                  // wave-uniform
    int bg = blockIdx.x % BG;
    int b  = bg * IPB + il;

    uint32_t* mybins = bins + il * STR;
    __syncthreads();

    for (int k = sub; k < K; k += SUB) {
        int xaddr;
        if (PERM) { int c = k / 25, yx = k % 25; xaddr = b * 400 + yx * 16 + c; }
        else      { xaddr = k * 128 + b; }
        int x = in_sym[xaddr];
        int w = wsym[m * K + k];
        int g = fcT[w * NC + x];
        atomicAdd(&mybins[g >> 3], 1u << ((g & 7) << 2));
    }
    __syncthreads();

    ScanN sc; sc.init(mybins);
    int t = sc.pop();
    for (int s = 1; s < K; ++s) t = add_lut[sc.pop() * NC + t];
    if (sub == 0)
        out[m * 128 + b] = relu_lut[bias_lut[t * M + m]];
}

__global__ __launch_bounds__(64) void k_fc1(
    const int* in, const int* wsym, const unsigned short* fcT,
    const int* add_lut, const int* bias, const int* relu, int* out)
{
    fc_body<120, 400, true, 16>(in, wsym, fcT, add_lut, bias, relu, out);
}

__global__ __launch_bounds__(64) void k_fc2(
    const int* in, const int* wsym, const unsigned short* fcT,
    const int* add_lut, const int* bias, const int* relu, int* out)
{
    fc_body<84, 120, false, 16>(in, wsym, fcT, add_lut, bias, relu, out);
}

// ===========================================================================
// Head — verified R1/R7 (m-major input).
// ===========================================================================
__global__ __launch_bounds__(64) void k_head(
    const int* __restrict__ f2m, const float* __restrict__ cent,
    const float* __restrict__ w, const float* __restrict__ bias,
    float* __restrict__ out)
{
    int b = blockIdx.x * 64 + threadIdx.x;
    float acc[10];
#pragma unroll
    for (int o = 0; o < 10; ++o) acc[o] = bias[o];
    for (int k = 0; k < 84; ++k) {
        float f = cent[f2m[k * 128 + b]];
#pragma unroll
        for (int o = 0; o < 10; ++o) acc[o] += f * w[o * 84 + k];
    }
    float mx = acc[0];
#pragma unroll
    for (int o = 1; o < 10; ++o) mx = fmaxf(mx, acc[o]);
    float s = 0.f;
#pragma unroll
    for (int o = 0; o < 10; ++o) { acc[o] = expf(acc[o] - mx); s += acc[o]; }
    float inv = 1.f / s;
#pragma unroll
    for (int o = 0; o < 10; ++o) out[b * 10 + o] = acc[o] * inv;
}

// ===========================================================================
extern "C" void kernel_launch(void* const* d_in, const int* in_sizes, int n_in,
                              void* d_out, int out_size, void* d_ws, size_t ws_size,
                              hipStream_t stream)
{
    const float* x_bat  = (const float*)d_in[0];
    const float* cent   = (const float*)d_in[1];
    const int* conv_lut = (const int*)d_in[2];
    const int* fc_lut   = (const int*)d_in[3];
    const int* add_lut  = (const int*)d_in[4];
    const int* relu_lut = (const int*)d_in[5];
    const int* c1_bias  = (const int*)d_in[6];
    const int* c2_bias  = (const int*)d_in[7];
    const int* f1_bias  = (const int*)d_in[8];
    const int* f2_bias  = (const int*)d_in[9];
    const int* c1f      = (const int*)d_in[10];
    const int* c2f      = (const int*)d_in[11];
    const int* f1f      = (const int*)d_in[12];
    const int* f2f      = (const int*)d_in[13];
    const float* fc3_w  = (const float*)d_in[14];
    const float* fc3_b  = (const float*)d_in[15];
    float* out = (float*)d_out;

    char* ws = (char*)d_ws;
    unsigned short* convT = (unsigned short*)(ws);            // 512 KB
    unsigned short* fcT   = (unsigned short*)(ws + 524288);   // 512 KB
    unsigned short* sym0  = (unsigned short*)(ws + 1048576);  // 256 KB
    unsigned short* c1o   = (unsigned short*)(ws + 1310720);  // 294 KB (b,14,14,6) u16
    int* c2o = (int*)(ws + 1611776);                          // 200 KB (b,5,5,16)
    int* f1o = (int*)(ws + 1816576);                          //  60 KB (120,128) m-major
    int* f2o = (int*)(ws + 1878016);                          //  42 KB (84,128)  m-major
    // peak ws ~1.92 MB

    k_transpose_pack<<<64, 256, 0, stream>>>(conv_lut, convT);
    k_transpose_pack<<<64, 256, 0, stream>>>(fc_lut, fcT);
    k_discretize<<<512, 256, 0, stream>>>(x_bat, cent, sym0);
    // conv1: SUB=4, 6 co x 1568 = 9408 blocks (36.7 waves/CU — saturated)
    k_conv1<<<9408, 64, 0, stream>>>(sym0, c1f, convT, add_lut, c1_bias, relu_lut, c1o);
    // conv2: SUB=8, 16 co x 800 = 6400 blocks (25 waves/CU)
    k_conv2<<<6400, 64, 0, stream>>>(c1o, c2f, convT, add_lut, c2_bias, relu_lut, c2o);
    // fc1: SUB=16, 120 m x 32 = 3840 blocks (15 waves/CU)
    k_fc1<<<3840, 64, 0, stream>>>(c2o, f1f, fcT, add_lut, f1_bias, relu_lut, f1o);
    // fc2: SUB=16, 84 m x 32 = 2688 blocks (10.5 waves/CU)
    k_fc2<<<2688, 64, 0, stream>>>(f1o, f2f, fcT, add_lut, f2_bias, relu_lut, f2o);
    k_head<<<2, 64, 0, stream>>>(f2o, cent, fc3_w, fc3_b, out);
}

// Round 10
// 763.340 us; speedup vs baseline: 1.2045x; 1.0706x over previous
//
#include <hip/hip_runtime.h>

#define NC 512   // N_CLUSTERS

// ===========================================================================
// Pre-pass: dstT[w][s] = (u16)src[s][w]  (verified R3/R5/R6/R7/R8/R9).
// ===========================================================================
__global__ __launch_bounds__(256) void k_transpose_pack(
    const int* __restrict__ src, unsigned short* __restrict__ dst)
{
    __shared__ unsigned short tile[64][65];
    int tx = blockIdx.x % 8, ty = blockIdx.x / 8;
    int lane = threadIdx.x & 63, grp = threadIdx.x >> 6;
    for (int r = grp * 16; r < grp * 16 + 16; ++r)
        tile[r][lane] = (unsigned short)src[(ty * 64 + r) * NC + tx * 64 + lane];
    __syncthreads();
    for (int r = grp * 16; r < grp * 16 + 16; ++r)
        dst[(tx * 64 + r) * NC + ty * 64 + lane] = tile[lane][r];
}

// ===========================================================================
// Stage 1: discretize -> u16 symbols (verified R1..R9).
// ===========================================================================
__global__ __launch_bounds__(256) void k_discretize(
    const float* __restrict__ x, const float* __restrict__ cent,
    unsigned short* __restrict__ out)
{
    __shared__ float c[NC];
    int tid = threadIdx.x;
    for (int i = tid; i < NC; i += 256) c[i] = cent[i];
    __syncthreads();
    int id = blockIdx.x * 256 + tid;   // 131072 exact
    float px = x[id];
    float best = fabsf(px - c[0]);
    int bi = 0;
    for (int k = 1; k < NC; ++k) {
        float d = fabsf(px - c[k]);
        if (d < best) { best = d; bi = k; }
    }
    out[id] = (unsigned short)bi;
}

// ===========================================================================
// Nibble-bin pop-min scanner (verified R4/R7/R8/R9). 512 bins packed 8/word;
// in-register window = 4 VGPRs (32 bins) + nonzero mask. insert() far-path is
// plain RMW: all redundant lanes of an instance write same addr/value => +1
// exactly once (verified R7/R9).
// ===========================================================================
struct ScanN {
    uint32_t* base;
    uint32_t w[4];
    uint32_t mask;
    int chunk;

    static __device__ inline uint32_t nz4b(uint32_t x) {
        uint32_t y = (x & 0x7F7F7F7Fu) + 0x7F7F7F7Fu;
        y = (y | x) & 0x80808080u;
        return (y * 0x00204081u) >> 28;
    }
    static __device__ inline uint32_t spread4(uint32_t v) {
        v = (v | (v << 2)) & 0x33u;
        v = (v | (v << 1)) & 0x55u;
        return v;
    }
    static __device__ inline uint32_t nzn(uint32_t x) {
        uint32_t lo = x & 0x0F0F0F0Fu;
        uint32_t hi = (x >> 4) & 0x0F0F0F0Fu;
        return spread4(nz4b(lo)) | (spread4(nz4b(hi)) << 1);
    }
    __device__ inline void init(uint32_t* b) { base = b; mask = 0; chunk = -1; }
    __device__ inline void load() {
        uint4 a = *(const uint4*)(base + chunk * 4);
        w[0] = a.x; w[1] = a.y; w[2] = a.z; w[3] = a.w;
        mask = nzn(w[0]) | (nzn(w[1]) << 8) | (nzn(w[2]) << 16) | (nzn(w[3]) << 24);
    }
    __device__ inline void ensure() { while (mask == 0) { ++chunk; load(); } }
    __device__ inline int  peek()   { ensure(); return chunk * 32 + (int)__builtin_ctz(mask); }
    __device__ inline void consume_min() {
        int k = (int)__builtin_ctz(mask);
        int dw = k >> 3, sh = (k & 7) << 2;
        uint32_t cnt = 0;
#pragma unroll
        for (int i = 0; i < 4; ++i) if (i == dw) { cnt = (w[i] >> sh) & 0xFu; w[i] -= (1u << sh); }
        if (cnt == 1) mask &= ~(1u << k);
    }
    __device__ inline int pop() { int v = peek(); consume_min(); return v; }
    __device__ inline void insert(int v) {
        int rel = v - chunk * 32;
        if (rel < 32) {
            int dw = rel >> 3, sh = (rel & 7) << 2;
#pragma unroll
            for (int i = 0; i < 4; ++i) if (i == dw) w[i] += (1u << sh);
            mask |= (1u << rel);
        } else {
            uint32_t old = base[v >> 3];
            base[v >> 3] = old + (1u << ((v & 7) << 2));
        }
    }
};

// ===========================================================================
// Cooperative symbolic conv, _conv_reduce semantics (verified R1/R2/R5/R7/R9).
// 64 threads = (64/SUB) instances x SUB redundant lanes.
// ===========================================================================
template<typename IT, typename OT, int CIN, int CO, int IH, int IW, int OH, int OW, int SUB>
__device__ __forceinline__ void conv_body(
    const IT* __restrict__ in_sym, const int* __restrict__ wsym,
    const unsigned short* __restrict__ convT, const int* __restrict__ add_lut,
    const int* __restrict__ bias_lut, const int* __restrict__ relu_lut,
    OT* __restrict__ out)
{
    constexpr int N    = 25 * CIN;
    constexpr int PPI  = OH * OW;
    constexpr int IPB  = 64 / SUB;              // instances per block
    constexpr int BPC  = (128 * PPI) / IPB;     // blocks per co (exact)
    constexpr int STR  = 68;
    __shared__ __align__(16) uint32_t bins[IPB * STR];
    int tid = threadIdx.x;
    int il  = tid / SUB;
    int sub = tid % SUB;

    for (int i = tid; i < IPB * STR; i += 64) bins[i] = 0u;

    int posg = blockIdx.x % BPC;
    int co   = blockIdx.x / BPC;                // wave-uniform
    int pos  = posg * IPB + il;
    int b  = pos / PPI;
    int yx = pos % PPI;
    int oy = yx / OW, ox = yx % OW;

    uint32_t* mybins = bins + il * STR;
    __syncthreads();

    for (int n = sub; n < N; n += SUB) {
        int i   = n / (5 * CIN);
        int rem = n % (5 * CIN);
        int j   = rem / CIN;
        int c   = rem % CIN;
        int s = (int)in_sym[((b * IH + (oy * 2 + i)) * IW + (ox * 2 + j)) * CIN + c];
        int w = wsym[n * CO + co];
        int g = convT[w * NC + s];
        atomicAdd(&mybins[g >> 3], 1u << ((g & 7) << 2));
    }
    __syncthreads();

    // Fold: all SUB lanes of an instance run the identical chain (lockstep).
    ScanN sc; sc.init(mybins);
    int t = sc.pop();
    for (int j = 1; j < N; ++j) {
        int x = sc.pop();
        int t2 = add_lut[x * NC + t];           // IPB distinct lines per wave
        if (j < N - 2) {
            int y = sc.peek();
            if (t2 > y) { sc.consume_min(); sc.insert(t2); t = y; }
            else t = t2;
        } else t = t2;
    }
    if (sub == 0)
        out[pos * CO + co] = (OT)relu_lut[bias_lut[t * CO + co]];
}

__global__ __launch_bounds__(64) void k_conv1(
    const unsigned short* in, const int* wsym, const unsigned short* convT,
    const int* add_lut, const int* bias, const int* relu, unsigned short* out)
{
    conv_body<unsigned short, unsigned short, 1, 6, 32, 32, 14, 14, 4>(
        in, wsym, convT, add_lut, bias, relu, out);
}

__global__ __launch_bounds__(64) void k_conv2(
    const unsigned short* in, const int* wsym, const unsigned short* convT,
    const int* add_lut, const int* bias, const int* relu, int* out)
{
    // SUB=4: R7's proven best (318 us; R9's SUB=8 was 330)
    conv_body<unsigned short, int, 6, 16, 14, 14, 5, 5, 4>(
        in, wsym, convT, add_lut, bias, relu, out);
}

// ===========================================================================
// Cooperative symbolic FC, _fc_reduce = ascending pops (verified R1/R2/R7/R9).
// SUB=8 this round: fc1 7.5 waves/CU (rising region of measured saturation
// curve), vs R7's starved 3.75 (SUB=4) and R9's overshot SUB=16.
// ===========================================================================
template<int M, int K, bool PERM, int SUB>
__device__ __forceinline__ void fc_body(
    const int* __restrict__ in_sym, const int* __restrict__ wsym,
    const unsigned short* __restrict__ fcT, const int* __restrict__ add_lut,
    const int* __restrict__ bias_lut, const int* __restrict__ relu_lut,
    int* __restrict__ out)
{
    constexpr int IPB = 64 / SUB;
    constexpr int BG  = 128 / IPB;             // batch groups
    constexpr int STR = 68;
    __shared__ __align__(16) uint32_t bins[IPB * STR];
    int tid = threadIdx.x;
    int il  = tid / SUB;
    int sub = tid % SUB;

    for (int i = tid; i < IPB * STR; i += 64) bins[i] = 0u;

    int m  = blockIdx.x / BG;                  // wave-uniform
    int bg = blockIdx.x % BG;
    int b  = bg * IPB + il;

    uint32_t* mybins = bins + il * STR;
    __syncthreads();

    for (int k = sub; k < K; k += SUB) {
        int xaddr;
        if (PERM) { int c = k / 25, yx = k % 25; xaddr = b * 400 + yx * 16 + c; }
        else      { xaddr = k * 128 + b; }
        int x = in_sym[xaddr];
        int w = wsym[m * K + k];
        int g = fcT[w * NC + x];
        atomicAdd(&mybins[g >> 3], 1u << ((g & 7) << 2));
    }
    __syncthreads();

    ScanN sc; sc.init(mybins);
    int t = sc.pop();
    for (int s = 1; s < K; ++s) t = add_lut[sc.pop() * NC + t];
    if (sub == 0)
        out[m * 128 + b] = relu_lut[bias_lut[t * M + m]];
}

__global__ __launch_bounds__(64) void k_fc1(
    const int* in, const int* wsym, const unsigned short* fcT,
    const int* add_lut, const int* bias, const int* relu, int* out)
{
    fc_body<120, 400, true, 8>(in, wsym, fcT, add_lut, bias, relu, out);
}

__global__ __launch_bounds__(64) void k_fc2(
    const int* in, const int* wsym, const unsigned short* fcT,
    const int* add_lut, const int* bias, const int* relu, int* out)
{
    fc_body<84, 120, false, 8>(in, wsym, fcT, add_lut, bias, relu, out);
}

// ===========================================================================
// Head — verified R1/R7 (m-major input).
// ===========================================================================
__global__ __launch_bounds__(64) void k_head(
    const int* __restrict__ f2m, const float* __restrict__ cent,
    const float* __restrict__ w, const float* __restrict__ bias,
    float* __restrict__ out)
{
    int b = blockIdx.x * 64 + threadIdx.x;
    float acc[10];
#pragma unroll
    for (int o = 0; o < 10; ++o) acc[o] = bias[o];
    for (int k = 0; k < 84; ++k) {
        float f = cent[f2m[k * 128 + b]];
#pragma unroll
        for (int o = 0; o < 10; ++o) acc[o] += f * w[o * 84 + k];
    }
    float mx = acc[0];
#pragma unroll
    for (int o = 1; o < 10; ++o) mx = fmaxf(mx, acc[o]);
    float s = 0.f;
#pragma unroll
    for (int o = 0; o < 10; ++o) { acc[o] = expf(acc[o] - mx); s += acc[o]; }
    float inv = 1.f / s;
#pragma unroll
    for (int o = 0; o < 10; ++o) out[b * 10 + o] = acc[o] * inv;
}

// ===========================================================================
extern "C" void kernel_launch(void* const* d_in, const int* in_sizes, int n_in,
                              void* d_out, int out_size, void* d_ws, size_t ws_size,
                              hipStream_t stream)
{
    const float* x_bat  = (const float*)d_in[0];
    const float* cent   = (const float*)d_in[1];
    const int* conv_lut = (const int*)d_in[2];
    const int* fc_lut   = (const int*)d_in[3];
    const int* add_lut  = (const int*)d_in[4];
    const int* relu_lut = (const int*)d_in[5];
    const int* c1_bias  = (const int*)d_in[6];
    const int* c2_bias  = (const int*)d_in[7];
    const int* f1_bias  = (const int*)d_in[8];
    const int* f2_bias  = (const int*)d_in[9];
    const int* c1f      = (const int*)d_in[10];
    const int* c2f      = (const int*)d_in[11];
    const int* f1f      = (const int*)d_in[12];
    const int* f2f      = (const int*)d_in[13];
    const float* fc3_w  = (const float*)d_in[14];
    const float* fc3_b  = (const float*)d_in[15];
    float* out = (float*)d_out;

    char* ws = (char*)d_ws;
    unsigned short* convT = (unsigned short*)(ws);            // 512 KB
    unsigned short* fcT   = (unsigned short*)(ws + 524288);   // 512 KB
    unsigned short* sym0  = (unsigned short*)(ws + 1048576);  // 256 KB
    unsigned short* c1o   = (unsigned short*)(ws + 1310720);  // 294 KB (b,14,14,6) u16
    int* c2o = (int*)(ws + 1611776);                          // 200 KB (b,5,5,16)
    int* f1o = (int*)(ws + 1816576);                          //  60 KB (120,128) m-major
    int* f2o = (int*)(ws + 1878016);                          //  42 KB (84,128)  m-major
    // peak ws ~1.92 MB

    k_transpose_pack<<<64, 256, 0, stream>>>(conv_lut, convT);
    k_transpose_pack<<<64, 256, 0, stream>>>(fc_lut, fcT);
    k_discretize<<<512, 256, 0, stream>>>(x_bat, cent, sym0);
    // conv1: SUB=4, 9408 blocks (36.7 waves/CU)  [R7 verbatim]
    k_conv1<<<9408, 64, 0, stream>>>(sym0, c1f, convT, add_lut, c1_bias, relu_lut, c1o);
    // conv2: SUB=4, 3200 blocks (12.5 waves/CU)  [R7 verbatim — 318 us]
    k_conv2<<<3200, 64, 0, stream>>>(c1o, c2f, convT, add_lut, c2_bias, relu_lut, c2o);
    // fc1: SUB=8, 120 m x 16 = 1920 blocks (7.5 waves/CU)
    k_fc1<<<1920, 64, 0, stream>>>(c2o, f1f, fcT, add_lut, f1_bias, relu_lut, f1o);
    // fc2: SUB=8, 84 m x 16 = 1344 blocks (5.25 waves/CU)
    k_fc2<<<1344, 64, 0, stream>>>(f1o, f2f, fcT, add_lut, f2_bias, relu_lut, f2o);
    k_head<<<2, 64, 0, stream>>>(f2o, cent, fc3_w, fc3_b, out);
}